// Round 2
// baseline (3159.086 us; speedup 1.0000x reference)
//
#include <hip/hip_runtime.h>

// PlayerPerformanceGNN: 2-layer GCN (32->16->8) + mean-pool + linear (8->5)
// N=1M, E=16M, G=10k.
// Round 1: device-built CSR (count -> 2-level scan -> scatter), pull-based
// aggregation with fused normalize+bias+ReLU (+pool for conv2). Atomics:
// 32M int (CSR build) + 8M f32 (pool) vs 408M f32 in round 0.
// Fallback to round-0 scatter path if ws_size < ~205 MB.

namespace {

constexpr int F_IN = 32, F_H1 = 16, F_H2 = 8, N_CLS = 5;
constexpr int SCAN_BLK = 256, SCAN_ELEMS = 1024;  // 4 elems/thread

// ---------- shared small kernels ----------

__global__ void k_mm1(const float* __restrict__ x, const float* __restrict__ W,
                      float* __restrict__ h, int N) {
  __shared__ float w[F_IN * F_H1];
  for (int k = threadIdx.x; k < F_IN * F_H1; k += blockDim.x) w[k] = W[k];
  __syncthreads();
  int i = blockIdx.x * blockDim.x + threadIdx.x;
  if (i >= N) return;
  const float4* xr = reinterpret_cast<const float4*>(x + (size_t)i * F_IN);
  float acc[F_H1];
#pragma unroll
  for (int f = 0; f < F_H1; ++f) acc[f] = 0.f;
#pragma unroll
  for (int k4 = 0; k4 < F_IN / 4; ++k4) {
    float4 v = xr[k4];
    float vv[4] = {v.x, v.y, v.z, v.w};
#pragma unroll
    for (int j = 0; j < 4; ++j) {
      const float* wr = &w[(k4 * 4 + j) * F_H1];
#pragma unroll
      for (int f = 0; f < F_H1; ++f) acc[f] = fmaf(vv[j], wr[f], acc[f]);
    }
  }
  float4* hr = reinterpret_cast<float4*>(h + (size_t)i * F_H1);
#pragma unroll
  for (int q = 0; q < F_H1 / 4; ++q)
    hr[q] = make_float4(acc[q * 4], acc[q * 4 + 1], acc[q * 4 + 2], acc[q * 4 + 3]);
}

__global__ void k_mm2(const float* __restrict__ in, const float* __restrict__ W,
                      float* __restrict__ h, int N) {
  __shared__ float w[F_H1 * F_H2];
  for (int k = threadIdx.x; k < F_H1 * F_H2; k += blockDim.x) w[k] = W[k];
  __syncthreads();
  int i = blockIdx.x * blockDim.x + threadIdx.x;
  if (i >= N) return;
  const float4* xr = reinterpret_cast<const float4*>(in + (size_t)i * F_H1);
  float acc[F_H2];
#pragma unroll
  for (int f = 0; f < F_H2; ++f) acc[f] = 0.f;
#pragma unroll
  for (int k4 = 0; k4 < F_H1 / 4; ++k4) {
    float4 v = xr[k4];
    float vv[4] = {v.x, v.y, v.z, v.w};
#pragma unroll
    for (int j = 0; j < 4; ++j) {
      const float* wr = &w[(k4 * 4 + j) * F_H2];
#pragma unroll
      for (int f = 0; f < F_H2; ++f) acc[f] = fmaf(vv[j], wr[f], acc[f]);
    }
  }
  float4* hr = reinterpret_cast<float4*>(h + (size_t)i * F_H2);
#pragma unroll
  for (int q = 0; q < F_H2 / 4; ++q)
    hr[q] = make_float4(acc[q * 4], acc[q * 4 + 1], acc[q * 4 + 2], acc[q * 4 + 3]);
}

__global__ void k_final(const float* __restrict__ pooled, const float* __restrict__ cnts,
                        const float* __restrict__ Wl, const float* __restrict__ bl,
                        float* __restrict__ out, int total) {
  int gid = blockIdx.x * blockDim.x + threadIdx.x;
  if (gid >= total) return;
  int g = gid / N_CLS, c = gid % N_CLS;
  float s = 0.f;
#pragma unroll
  for (int f = 0; f < F_H2; ++f) s += pooled[g * F_H2 + f] * Wl[f * N_CLS + c];
  out[gid] = s / fmaxf(cnts[g], 1.f) + bl[c];
}

// ---------- fast path: CSR build ----------

__global__ void k_count(const int* __restrict__ dst, int* __restrict__ cnt, int E) {
  int e = blockIdx.x * blockDim.x + threadIdx.x;
  if (e < E) atomicAdd(&cnt[dst[e]], 1);
}

__global__ void k_scan1(const int* __restrict__ cnt, int* __restrict__ blk, int N) {
  __shared__ int s[SCAN_BLK];
  int b = blockIdx.x, t = threadIdx.x;
  int base = b * SCAN_ELEMS + t * 4;
  int v = 0;
#pragma unroll
  for (int k = 0; k < 4; ++k) {
    int i = base + k;
    if (i < N) v += cnt[i];
  }
  s[t] = v;
  __syncthreads();
  for (int off = SCAN_BLK / 2; off > 0; off >>= 1) {
    if (t < off) s[t] += s[t + off];
    __syncthreads();
  }
  if (t == 0) blk[b] = s[0];
}

__global__ void k_scan2(int* __restrict__ blk, int NB, int* __restrict__ row_ptr,
                        int N, int E) {
  __shared__ int s[1024];
  int t = threadIdx.x;
  int v = (t < NB) ? blk[t] : 0;
  s[t] = v;
  __syncthreads();
  for (int off = 1; off < 1024; off <<= 1) {
    int x = (t >= off) ? s[t - off] : 0;
    __syncthreads();
    s[t] += x;
    __syncthreads();
  }
  if (t < NB) blk[t] = s[t] - v;  // exclusive block offsets
  if (t == 0) row_ptr[N] = E;
}

// cnt is consumed and rewritten as the scatter cursor (= row_ptr copy).
__global__ void k_scan3(int* __restrict__ cnt, const int* __restrict__ blk,
                        int* __restrict__ row_ptr, float* __restrict__ dis, int N) {
  __shared__ int s[SCAN_BLK];
  int b = blockIdx.x, t = threadIdx.x;
  int base = b * SCAN_ELEMS + t * 4;
  int v[4];
  int sum = 0;
#pragma unroll
  for (int k = 0; k < 4; ++k) {
    int i = base + k;
    v[k] = (i < N) ? cnt[i] : 0;
    sum += v[k];
  }
  s[t] = sum;
  __syncthreads();
  for (int off = 1; off < SCAN_BLK; off <<= 1) {
    int x = (t >= off) ? s[t - off] : 0;
    __syncthreads();
    s[t] += x;
    __syncthreads();
  }
  int run = blk[b] + s[t] - sum;  // exclusive prefix for this thread's first elem
#pragma unroll
  for (int k = 0; k < 4; ++k) {
    int i = base + k;
    if (i < N) {
      row_ptr[i] = run;
      cnt[i] = run;  // cursor
      dis[i] = rsqrtf((float)v[k] + 1.0f);
      run += v[k];
    }
  }
}

__global__ void k_scatter(const int* __restrict__ src, const int* __restrict__ dst,
                          int* __restrict__ cursor, int* __restrict__ csr, int E) {
  int e = blockIdx.x * blockDim.x + threadIdx.x;
  if (e >= E) return;
  int d = dst[e];
  int pos = atomicAdd(&cursor[d], 1);
  csr[pos] = src[e];
}

// ---------- fast path: pull aggregation ----------

template <int F>
__global__ void k_pull(const int* __restrict__ row_ptr, const int* __restrict__ csr,
                       const float* __restrict__ dis, const float* __restrict__ h,
                       const float* __restrict__ b, float* __restrict__ out, int N) {
  int t = threadIdx.x;
  int node = blockIdx.x * (256 / F) + t / F;
  int f = t % F;
  if (node >= N) return;
  int beg = row_ptr[node], end = row_ptr[node + 1];
  float self = h[(size_t)node * F + f];
  float acc = 0.f;
  int e = beg;
  for (; e + 1 < end; e += 2) {  // x2 unroll: two independent gathers in flight
    int s0 = csr[e], s1 = csr[e + 1];
    acc = fmaf(dis[s0], h[(size_t)s0 * F + f], acc);
    acc = fmaf(dis[s1], h[(size_t)s1 * F + f], acc);
  }
  if (e < end) {
    int s0 = csr[e];
    acc = fmaf(dis[s0], h[(size_t)s0 * F + f], acc);
  }
  float di = dis[node];
  out[(size_t)node * F + f] = fmaxf(fmaf(di, acc, fmaf(self, di * di, b[f])), 0.f);
}

__global__ void k_pull_pool(const int* __restrict__ row_ptr, const int* __restrict__ csr,
                            const float* __restrict__ dis, const float* __restrict__ h,
                            const float* __restrict__ b, const int* __restrict__ batch,
                            float* __restrict__ pooled, float* __restrict__ cnts, int N) {
  int t = threadIdx.x;
  int node = blockIdx.x * (256 / F_H2) + t / F_H2;
  int f = t % F_H2;
  if (node >= N) return;
  int beg = row_ptr[node], end = row_ptr[node + 1];
  float self = h[(size_t)node * F_H2 + f];
  float acc = 0.f;
  int e = beg;
  for (; e + 1 < end; e += 2) {
    int s0 = csr[e], s1 = csr[e + 1];
    acc = fmaf(dis[s0], h[(size_t)s0 * F_H2 + f], acc);
    acc = fmaf(dis[s1], h[(size_t)s1 * F_H2 + f], acc);
  }
  if (e < end) {
    int s0 = csr[e];
    acc = fmaf(dis[s0], h[(size_t)s0 * F_H2 + f], acc);
  }
  float di = dis[node];
  float v = fmaxf(fmaf(di, acc, fmaf(self, di * di, b[f])), 0.f);
  int g = batch[node];
  atomicAdd(&pooled[g * F_H2 + f], v);
  if (f == 0) atomicAdd(&cnts[g], 1.0f);
}

// ---------- fallback path (round-0 scatter atomics) ----------

__global__ void k_deg(const int* __restrict__ dst, float* __restrict__ deg, int E) {
  int e = blockIdx.x * blockDim.x + threadIdx.x;
  if (e < E) atomicAdd(&deg[dst[e]], 1.0f);
}
__global__ void k_dis(float* __restrict__ d, int N) {
  int i = blockIdx.x * blockDim.x + threadIdx.x;
  if (i < N) d[i] = rsqrtf(d[i] + 1.0f);
}
template <int F>
__global__ void k_edge(const int* __restrict__ src, const int* __restrict__ dst,
                       const float* __restrict__ dis, const float* __restrict__ h,
                       float* __restrict__ agg, int total) {
  int gid = blockIdx.x * blockDim.x + threadIdx.x;
  if (gid >= total) return;
  int e = gid / F, f = gid % F;
  int s = src[e], d = dst[e];
  atomicAdd(&agg[d * F + f], h[s * F + f] * dis[s] * dis[d]);
}
template <int F>
__global__ void k_combine(const float* __restrict__ h, const float* __restrict__ dis,
                          const float* __restrict__ b, float* __restrict__ agg, int total) {
  int gid = blockIdx.x * blockDim.x + threadIdx.x;
  if (gid >= total) return;
  int i = gid / F, f = gid % F;
  float di = dis[i];
  agg[gid] = fmaxf(agg[gid] + h[gid] * di * di + b[f], 0.f);
}
__global__ void k_combine_pool(const float* __restrict__ h2, const float* __restrict__ agg2,
                               const float* __restrict__ dis, const float* __restrict__ b,
                               const int* __restrict__ batch, float* __restrict__ pooled,
                               float* __restrict__ cnts, int total) {
  int gid = blockIdx.x * blockDim.x + threadIdx.x;
  if (gid >= total) return;
  int i = gid >> 3, f = gid & 7;
  float di = dis[i];
  float v = fmaxf(agg2[gid] + h2[gid] * di * di + b[f], 0.f);
  int g = batch[i];
  atomicAdd(&pooled[g * F_H2 + f], v);
  if (f == 0) atomicAdd(&cnts[g], 1.0f);
}

}  // namespace

extern "C" void kernel_launch(void* const* d_in, const int* in_sizes, int n_in,
                              void* d_out, int out_size, void* d_ws, size_t ws_size,
                              hipStream_t stream) {
  const float* x   = (const float*)d_in[0];
  const int* ei    = (const int*)d_in[1];
  const int* batch = (const int*)d_in[2];
  const float* W1 = (const float*)d_in[4];
  const float* b1 = (const float*)d_in[5];
  const float* W2 = (const float*)d_in[6];
  const float* b2 = (const float*)d_in[7];
  const float* Wl = (const float*)d_in[8];
  const float* bl = (const float*)d_in[9];

  const int N = in_sizes[0] / F_IN;   // 1,000,000
  const int E = in_sizes[1] / 2;      // 16,000,000
  const int G = out_size / N_CLS;     // 10,000
  const int* src  = ei;
  const int* dstp = ei + E;

  const int BLK = 256;
  const int NB = (N + SCAN_ELEMS - 1) / SCAN_ELEMS;

  // fast-path workspace requirement
  size_t need = (size_t)N * 4          // cnt / cursor
              + (size_t)(N + 4) * 4    // row_ptr (padded for 16B alignment)
              + (size_t)N * 4          // dis
              + (size_t)E * 4          // csr_src
              + (size_t)N * F_H1 * 4   // H  (h1, later h2)
              + (size_t)N * F_H1 * 4   // O  (out1)
              + (size_t)G * F_H2 * 4 + (size_t)G * 4 + 4096 * 4;

  if (ws_size >= need) {
    char* p = (char*)d_ws;
    int*   cnt     = (int*)p;    p += (size_t)N * 4;        // also cursor
    int*   row_ptr = (int*)p;    p += (size_t)(N + 4) * 4;
    float* dis     = (float*)p;  p += (size_t)N * 4;
    int*   csr     = (int*)p;    p += (size_t)E * 4;
    float* H       = (float*)p;  p += (size_t)N * F_H1 * 4; // h1; first half reused as h2
    float* O       = (float*)p;  p += (size_t)N * F_H1 * 4; // out1
    float* pooled  = (float*)p;  p += (size_t)G * F_H2 * 4;
    float* cnts    = (float*)p;  p += (size_t)G * 4;
    int*   blk     = (int*)p;
    float* h2 = H;

    hipMemsetAsync(cnt, 0, (size_t)N * 4, stream);
    hipMemsetAsync(pooled, 0, ((size_t)G * F_H2 + G) * 4, stream);

    // CSR build (reused for both convs) + dis
    k_count<<<(E + BLK - 1) / BLK, BLK, 0, stream>>>(dstp, cnt, E);
    k_scan1<<<NB, SCAN_BLK, 0, stream>>>(cnt, blk, N);
    k_scan2<<<1, 1024, 0, stream>>>(blk, NB, row_ptr, N, E);
    k_scan3<<<NB, SCAN_BLK, 0, stream>>>(cnt, blk, row_ptr, dis, N);
    k_scatter<<<(E + BLK - 1) / BLK, BLK, 0, stream>>>(src, dstp, cnt, csr, E);

    // conv1
    k_mm1<<<(N + BLK - 1) / BLK, BLK, 0, stream>>>(x, W1, H, N);
    k_pull<F_H1><<<(N * F_H1 + BLK - 1) / BLK, BLK, 0, stream>>>(
        row_ptr, csr, dis, H, b1, O, N);
    // conv2 (h1 dead -> h2 reuses H)
    k_mm2<<<(N + BLK - 1) / BLK, BLK, 0, stream>>>(O, W2, h2, N);
    k_pull_pool<<<(N * F_H2 + BLK - 1) / BLK, BLK, 0, stream>>>(
        row_ptr, csr, dis, h2, b2, batch, pooled, cnts, N);

    k_final<<<(G * N_CLS + BLK - 1) / BLK, BLK, 0, stream>>>(
        pooled, cnts, Wl, bl, (float*)d_out, G * N_CLS);
    return;
  }

  // ---------- fallback: round-0 scatter-atomic path ----------
  float* ws = (float*)d_ws;
  float* dis    = ws;
  float* A      = ws + N;
  float* B      = A + (size_t)N * F_H1;
  float* h2     = A;
  float* agg2   = A + (size_t)N * F_H2;
  float* pooled = B + (size_t)N * F_H1;
  float* cnts   = pooled + (size_t)G * F_H2;

  hipMemsetAsync(dis, 0, (size_t)N * sizeof(float), stream);
  hipMemsetAsync(B, 0, (size_t)N * F_H1 * sizeof(float), stream);
  hipMemsetAsync(pooled, 0, ((size_t)G * F_H2 + G) * sizeof(float), stream);

  k_deg<<<(E + BLK - 1) / BLK, BLK, 0, stream>>>(dstp, dis, E);
  k_dis<<<(N + BLK - 1) / BLK, BLK, 0, stream>>>(dis, N);
  k_mm1<<<(N + BLK - 1) / BLK, BLK, 0, stream>>>(x, W1, A, N);
  k_edge<F_H1><<<(E * F_H1 + BLK - 1) / BLK, BLK, 0, stream>>>(src, dstp, dis, A, B, E * F_H1);
  k_combine<F_H1><<<(N * F_H1 + BLK - 1) / BLK, BLK, 0, stream>>>(A, dis, b1, B, N * F_H1);
  hipMemsetAsync(agg2, 0, (size_t)N * F_H2 * sizeof(float), stream);
  k_mm2<<<(N + BLK - 1) / BLK, BLK, 0, stream>>>(B, W2, h2, N);
  k_edge<F_H2><<<(E * F_H2 + BLK - 1) / BLK, BLK, 0, stream>>>(src, dstp, dis, h2, agg2, E * F_H2);
  k_combine_pool<<<(N * F_H2 + BLK - 1) / BLK, BLK, 0, stream>>>(
      h2, agg2, dis, b2, batch, pooled, cnts, N * F_H2);
  k_final<<<(G * N_CLS + BLK - 1) / BLK, BLK, 0, stream>>>(
      pooled, cnts, Wl, bl, (float*)d_out, G * N_CLS);
}

// Round 3
// 2881.266 us; speedup vs baseline: 1.0964x; 1.0964x over previous
//
#include <hip/hip_runtime.h>

// PlayerPerformanceGNN: 2-layer GCN (32->16->8) + mean-pool + linear (8->5)
// N=1M, E=16M, G=10k.
// Round 2: bucket decomposition instead of per-node CSR.
//   - edges bucketed by dst>>10 via LDS-staged binned scatter (coalesced runs,
//     one packed int per edge: (dstLocal<<20)|src)
//   - convs: block-per-bucket, LDS accumulator (1024 x F floats), ds_add_f32;
//     fused norm+bias+ReLU (+ mean-pool atomics in conv2 epilogue)
//   - degrees counted per-bucket in LDS (k_dis_b); no global f32 scatter atomics
// R1 lesson: returning atomics + random 4B stores over a 64MB target wrote
// 1.09 GB to HBM (full-line evictions). All scattered writes now go through
// LDS staging / LDS accumulation.

namespace {

constexpr int F_IN = 32, F_H1 = 16, F_H2 = 8, N_CLS = 5;
constexpr int BB = 10, NPB = 1 << BB;   // nodes per bucket
constexpr int MAXB = 1024;              // bucket-table size (N <= 2^20)
constexpr int CHUNK = 12288;            // edges per binscatter block (48KB stage)

// ---------------- dense matmuls ----------------

__global__ void k_mm1(const float* __restrict__ x, const float* __restrict__ W,
                      float* __restrict__ h, int N) {
  __shared__ float w[F_IN * F_H1];
  for (int k = threadIdx.x; k < F_IN * F_H1; k += blockDim.x) w[k] = W[k];
  __syncthreads();
  int i = blockIdx.x * blockDim.x + threadIdx.x;
  if (i >= N) return;
  const float4* xr = reinterpret_cast<const float4*>(x + (size_t)i * F_IN);
  float acc[F_H1];
#pragma unroll
  for (int f = 0; f < F_H1; ++f) acc[f] = 0.f;
#pragma unroll
  for (int k4 = 0; k4 < F_IN / 4; ++k4) {
    float4 v = xr[k4];
    float vv[4] = {v.x, v.y, v.z, v.w};
#pragma unroll
    for (int j = 0; j < 4; ++j) {
      const float* wr = &w[(k4 * 4 + j) * F_H1];
#pragma unroll
      for (int f = 0; f < F_H1; ++f) acc[f] = fmaf(vv[j], wr[f], acc[f]);
    }
  }
  float4* hr = reinterpret_cast<float4*>(h + (size_t)i * F_H1);
#pragma unroll
  for (int q = 0; q < F_H1 / 4; ++q)
    hr[q] = make_float4(acc[q * 4], acc[q * 4 + 1], acc[q * 4 + 2], acc[q * 4 + 3]);
}

__global__ void k_mm2(const float* __restrict__ in, const float* __restrict__ W,
                      float* __restrict__ h, int N) {
  __shared__ float w[F_H1 * F_H2];
  for (int k = threadIdx.x; k < F_H1 * F_H2; k += blockDim.x) w[k] = W[k];
  __syncthreads();
  int i = blockIdx.x * blockDim.x + threadIdx.x;
  if (i >= N) return;
  const float4* xr = reinterpret_cast<const float4*>(in + (size_t)i * F_H1);
  float acc[F_H2];
#pragma unroll
  for (int f = 0; f < F_H2; ++f) acc[f] = 0.f;
#pragma unroll
  for (int k4 = 0; k4 < F_H1 / 4; ++k4) {
    float4 v = xr[k4];
    float vv[4] = {v.x, v.y, v.z, v.w};
#pragma unroll
    for (int j = 0; j < 4; ++j) {
      const float* wr = &w[(k4 * 4 + j) * F_H2];
#pragma unroll
      for (int f = 0; f < F_H2; ++f) acc[f] = fmaf(vv[j], wr[f], acc[f]);
    }
  }
  float4* hr = reinterpret_cast<float4*>(h + (size_t)i * F_H2);
#pragma unroll
  for (int q = 0; q < F_H2 / 4; ++q)
    hr[q] = make_float4(acc[q * 4], acc[q * 4 + 1], acc[q * 4 + 2], acc[q * 4 + 3]);
}

__global__ void k_final(const float* __restrict__ pooled, const float* __restrict__ cnts,
                        const float* __restrict__ Wl, const float* __restrict__ bl,
                        float* __restrict__ out, int total) {
  int gid = blockIdx.x * blockDim.x + threadIdx.x;
  if (gid >= total) return;
  int g = gid / N_CLS, c = gid % N_CLS;
  float s = 0.f;
#pragma unroll
  for (int f = 0; f < F_H2; ++f) s += pooled[g * F_H2 + f] * Wl[f * N_CLS + c];
  out[gid] = s / fmaxf(cnts[g], 1.f) + bl[c];
}

// ---------------- bucket build ----------------

__global__ void k_hist(const int* __restrict__ dst, int* __restrict__ bcnt,
                       int E, int nbuck) {
  __shared__ int h[MAXB];
  for (int i = threadIdx.x; i < MAXB; i += blockDim.x) h[i] = 0;
  __syncthreads();
  for (int e = blockIdx.x * blockDim.x + threadIdx.x; e < E;
       e += gridDim.x * blockDim.x)
    atomicAdd(&h[dst[e] >> BB], 1);
  __syncthreads();
  for (int i = threadIdx.x; i < nbuck; i += blockDim.x)
    if (h[i]) atomicAdd(&bcnt[i], h[i]);
}

// single block, MAXB threads: exclusive scan bcnt -> bbase (+copy to bcur)
__global__ void k_bscan(const int* __restrict__ bcnt, int* __restrict__ bbase,
                        int* __restrict__ bcur, int nbuck, int E) {
  __shared__ int s[MAXB];
  int t = threadIdx.x;
  int v = (t < nbuck) ? bcnt[t] : 0;
  s[t] = v;
  __syncthreads();
  for (int off = 1; off < MAXB; off <<= 1) {
    int x = (t >= off) ? s[t - off] : 0;
    __syncthreads();
    s[t] += x;
    __syncthreads();
  }
  int ex = s[t] - v;
  if (t < nbuck) { bbase[t] = ex; bcur[t] = ex; }
  if (t == 0) bbase[nbuck] = E;
}

// LDS-staged binned scatter: packed[pos] = (dstLocal<<20)|src, grouped by bucket
__global__ __launch_bounds__(256)
void k_binscatter(const int* __restrict__ dst, const int* __restrict__ src,
                  int* __restrict__ bcur, int* __restrict__ packed, int E) {
  __shared__ int hist[MAXB];       // chunk counts; rewritten as global base
  __shared__ int sbase[MAXB];      // exclusive scan of chunk counts
  __shared__ int lcur[MAXB];       // local cursor
  __shared__ int stg[CHUNK];       // staged packed edges, bucket order
  __shared__ int stmp[256];
  int t = threadIdx.x;
  int c0 = blockIdx.x * CHUNK;
  int n = min(CHUNK, E - c0);
  for (int i = t; i < MAXB; i += 256) hist[i] = 0;
  __syncthreads();
  for (int j = t; j < n; j += 256) atomicAdd(&hist[dst[c0 + j] >> BB], 1);
  __syncthreads();
  // exclusive scan (4 entries/thread)
  int v[4], sum = 0;
  int b4 = t * 4;
#pragma unroll
  for (int k = 0; k < 4; ++k) { v[k] = hist[b4 + k]; sum += v[k]; }
  stmp[t] = sum;
  __syncthreads();
  for (int off = 1; off < 256; off <<= 1) {
    int x = (t >= off) ? stmp[t - off] : 0;
    __syncthreads();
    stmp[t] += x;
    __syncthreads();
  }
  int run = stmp[t] - sum;
#pragma unroll
  for (int k = 0; k < 4; ++k) { sbase[b4 + k] = run; lcur[b4 + k] = run; run += v[k]; }
  __syncthreads();
  // reserve one contiguous global range per (block,bucket); hist becomes gbase
  for (int i = t; i < MAXB; i += 256) {
    int c = hist[i];
    if (c) hist[i] = atomicAdd(&bcur[i], c);
  }
  __syncthreads();
  // stage chunk edges in bucket order
  for (int j = t; j < n; j += 256) {
    int d = dst[c0 + j], s = src[c0 + j];
    int b = d >> BB;
    int p = atomicAdd(&lcur[b], 1);
    stg[p] = ((d & (NPB - 1)) << 20) | s;
  }
  __syncthreads();
  // write out: consecutive j in same bucket -> coalesced runs
  for (int j = t; j < n; j += 256) {
    int lo = 0, hi = MAXB - 1;
    while (lo < hi) {  // max b with sbase[b] <= j
      int mid = (lo + hi + 1) >> 1;
      if (sbase[mid] <= j) lo = mid; else hi = mid - 1;
    }
    packed[hist[lo] + (j - sbase[lo])] = stg[j];
  }
}

// per-bucket degree count -> dis = rsqrt(deg+1)
__global__ void k_dis_b(const int* __restrict__ bbase, const int* __restrict__ packed,
                        float* __restrict__ dis, int N) {
  __shared__ int cnt[NPB];
  int t = threadIdx.x;
  for (int i = t; i < NPB; i += blockDim.x) cnt[i] = 0;
  __syncthreads();
  int b = blockIdx.x;
  int beg = bbase[b], end = bbase[b + 1];
  for (int e = beg + t; e < end; e += blockDim.x)
    atomicAdd(&cnt[packed[e] >> 20], 1);
  __syncthreads();
  int node0 = b << BB;
  for (int i = t; i < NPB; i += blockDim.x) {
    int node = node0 + i;
    if (node < N) dis[node] = rsqrtf((float)cnt[i] + 1.0f);
  }
}

// ---------------- bucketed conv (LDS accumulate) ----------------
// out_i = relu( dis_i * sum_{j->i} dis_j h_j + dis_i^2 h_i + b )

template <int F>
__global__ __launch_bounds__(512)
void k_conv(const int* __restrict__ bbase, const int* __restrict__ packed,
            const float* __restrict__ dis, const float* __restrict__ h,
            const float* __restrict__ bias, float* __restrict__ out, int N) {
  __shared__ float acc[NPB * F];  // F=16: 64KB
  int t = threadIdx.x;
  for (int i = t; i < NPB * F; i += 512) acc[i] = 0.f;
  __syncthreads();
  int b = blockIdx.x;
  int beg = bbase[b], end = bbase[b + 1];
  const int EPI = 512 / F;
  int f = t % F, eg = t / F;
  for (int e = beg + eg; e < end; e += 2 * EPI) {
    int p0 = packed[e];
    int s0 = p0 & ((1 << 20) - 1), d0 = p0 >> 20;
    float m0 = dis[s0] * h[(size_t)s0 * F + f];
    int e1 = e + EPI;
    if (e1 < end) {
      int p1 = packed[e1];
      int s1 = p1 & ((1 << 20) - 1), d1 = p1 >> 20;
      float m1 = dis[s1] * h[(size_t)s1 * F + f];
      atomicAdd(&acc[d0 * F + f], m0);
      atomicAdd(&acc[d1 * F + f], m1);
    } else {
      atomicAdd(&acc[d0 * F + f], m0);
    }
  }
  __syncthreads();
  int node0 = b << BB;
  for (int i = t; i < NPB * F; i += 512) {
    int node = node0 + i / F;
    if (node >= N) continue;
    int ff = i % F;
    float di = dis[node];
    float v = fmaf(di, acc[i], fmaf(di * di, h[(size_t)node * F + ff], bias[ff]));
    out[(size_t)node * F + ff] = fmaxf(v, 0.f);
  }
}

// conv2 + mean-pool epilogue (no h_out write)
__global__ __launch_bounds__(512)
void k_conv_pool(const int* __restrict__ bbase, const int* __restrict__ packed,
                 const float* __restrict__ dis, const float* __restrict__ h,
                 const float* __restrict__ bias, const int* __restrict__ batch,
                 float* __restrict__ pooled, float* __restrict__ cnts, int N) {
  constexpr int F = F_H2;
  __shared__ float acc[NPB * F];  // 32KB
  int t = threadIdx.x;
  for (int i = t; i < NPB * F; i += 512) acc[i] = 0.f;
  __syncthreads();
  int b = blockIdx.x;
  int beg = bbase[b], end = bbase[b + 1];
  const int EPI = 512 / F;
  int f = t % F, eg = t / F;
  for (int e = beg + eg; e < end; e += 2 * EPI) {
    int p0 = packed[e];
    int s0 = p0 & ((1 << 20) - 1), d0 = p0 >> 20;
    float m0 = dis[s0] * h[(size_t)s0 * F + f];
    int e1 = e + EPI;
    if (e1 < end) {
      int p1 = packed[e1];
      int s1 = p1 & ((1 << 20) - 1), d1 = p1 >> 20;
      float m1 = dis[s1] * h[(size_t)s1 * F + f];
      atomicAdd(&acc[d0 * F + f], m0);
      atomicAdd(&acc[d1 * F + f], m1);
    } else {
      atomicAdd(&acc[d0 * F + f], m0);
    }
  }
  __syncthreads();
  int node0 = b << BB;
  for (int i = t; i < NPB * F; i += 512) {
    int node = node0 + i / F;
    if (node >= N) continue;
    int ff = i % F;
    float di = dis[node];
    float v = fmaf(di, acc[i], fmaf(di * di, h[(size_t)node * F + ff], bias[ff]));
    v = fmaxf(v, 0.f);
    int g = batch[node];
    atomicAdd(&pooled[g * F_H2 + ff], v);
    if (ff == 0) atomicAdd(&cnts[g], 1.0f);
  }
}

// ---------------- fallback (round-0 scatter atomics) ----------------

__global__ void k_deg(const int* __restrict__ dst, float* __restrict__ deg, int E) {
  int e = blockIdx.x * blockDim.x + threadIdx.x;
  if (e < E) atomicAdd(&deg[dst[e]], 1.0f);
}
__global__ void k_dis(float* __restrict__ d, int N) {
  int i = blockIdx.x * blockDim.x + threadIdx.x;
  if (i < N) d[i] = rsqrtf(d[i] + 1.0f);
}
template <int F>
__global__ void k_edge(const int* __restrict__ src, const int* __restrict__ dst,
                       const float* __restrict__ dis, const float* __restrict__ h,
                       float* __restrict__ agg, int total) {
  int gid = blockIdx.x * blockDim.x + threadIdx.x;
  if (gid >= total) return;
  int e = gid / F, f = gid % F;
  int s = src[e], d = dst[e];
  atomicAdd(&agg[d * F + f], h[s * F + f] * dis[s] * dis[d]);
}
template <int F>
__global__ void k_combine(const float* __restrict__ h, const float* __restrict__ dis,
                          const float* __restrict__ b, float* __restrict__ agg, int total) {
  int gid = blockIdx.x * blockDim.x + threadIdx.x;
  if (gid >= total) return;
  int i = gid / F, f = gid % F;
  float di = dis[i];
  agg[gid] = fmaxf(agg[gid] + h[gid] * di * di + b[f], 0.f);
}
__global__ void k_combine_pool_fb(const float* __restrict__ h2, const float* __restrict__ agg2,
                                  const float* __restrict__ dis, const float* __restrict__ b,
                                  const int* __restrict__ batch, float* __restrict__ pooled,
                                  float* __restrict__ cnts, int total) {
  int gid = blockIdx.x * blockDim.x + threadIdx.x;
  if (gid >= total) return;
  int i = gid >> 3, f = gid & 7;
  float di = dis[i];
  float v = fmaxf(agg2[gid] + h2[gid] * di * di + b[f], 0.f);
  int g = batch[i];
  atomicAdd(&pooled[g * F_H2 + f], v);
  if (f == 0) atomicAdd(&cnts[g], 1.0f);
}

}  // namespace

extern "C" void kernel_launch(void* const* d_in, const int* in_sizes, int n_in,
                              void* d_out, int out_size, void* d_ws, size_t ws_size,
                              hipStream_t stream) {
  const float* x   = (const float*)d_in[0];
  const int* ei    = (const int*)d_in[1];
  const int* batch = (const int*)d_in[2];
  const float* W1 = (const float*)d_in[4];
  const float* b1 = (const float*)d_in[5];
  const float* W2 = (const float*)d_in[6];
  const float* b2 = (const float*)d_in[7];
  const float* Wl = (const float*)d_in[8];
  const float* bl = (const float*)d_in[9];

  const int N = in_sizes[0] / F_IN;   // 1,000,000
  const int E = in_sizes[1] / 2;      // 16,000,000
  const int G = out_size / N_CLS;     // 10,000
  const int* src  = ei;
  const int* dstp = ei + E;

  const int BLK = 256;
  const int nbuck = (N + NPB - 1) >> BB;

  size_t need = (size_t)(3 * MAXB + 8) * 4   // bcnt, bbase, bcur
              + (size_t)E * 4                // packed
              + (size_t)N * 4                // dis
              + (size_t)N * F_H1 * 4         // H (h1, later h2)
              + (size_t)N * F_H1 * 4         // O (out1)
              + (size_t)G * (F_H2 + 1) * 4 + 1024;

  if (N <= (1 << 20) && nbuck <= MAXB && ws_size >= need) {
    char* p = (char*)d_ws;
    int*   bcnt   = (int*)p;    p += (size_t)MAXB * 4;
    int*   bbase  = (int*)p;    p += (size_t)(MAXB + 4) * 4;
    int*   bcur   = (int*)p;    p += (size_t)MAXB * 4;
    int*   packed = (int*)p;    p += (size_t)E * 4;
    float* dis    = (float*)p;  p += (size_t)N * 4;
    float* H      = (float*)p;  p += (size_t)N * F_H1 * 4;
    float* O      = (float*)p;  p += (size_t)N * F_H1 * 4;
    float* pooled = (float*)p;  p += (size_t)G * F_H2 * 4;
    float* cnts   = (float*)p;

    hipMemsetAsync(bcnt, 0, (size_t)MAXB * 4, stream);
    hipMemsetAsync(pooled, 0, ((size_t)G * F_H2 + G) * 4, stream);

    // bucket build
    k_hist<<<2048, BLK, 0, stream>>>(dstp, bcnt, E, nbuck);
    k_bscan<<<1, MAXB, 0, stream>>>(bcnt, bbase, bcur, nbuck, E);
    k_binscatter<<<(E + CHUNK - 1) / CHUNK, BLK, 0, stream>>>(dstp, src, bcur, packed, E);
    k_dis_b<<<nbuck, BLK, 0, stream>>>(bbase, packed, dis, N);

    // conv1
    k_mm1<<<(N + BLK - 1) / BLK, BLK, 0, stream>>>(x, W1, H, N);
    k_conv<F_H1><<<nbuck, 512, 0, stream>>>(bbase, packed, dis, H, b1, O, N);
    // conv2 (h2 reuses H)
    k_mm2<<<(N + BLK - 1) / BLK, BLK, 0, stream>>>(O, W2, H, N);
    k_conv_pool<<<nbuck, 512, 0, stream>>>(bbase, packed, dis, H, b2, batch,
                                           pooled, cnts, N);

    k_final<<<(G * N_CLS + BLK - 1) / BLK, BLK, 0, stream>>>(
        pooled, cnts, Wl, bl, (float*)d_out, G * N_CLS);
    return;
  }

  // ---------- fallback: round-0 scatter-atomic path ----------
  float* ws = (float*)d_ws;
  float* dis    = ws;
  float* A      = ws + N;
  float* B      = A + (size_t)N * F_H1;
  float* h2     = A;
  float* agg2   = A + (size_t)N * F_H2;
  float* pooled = B + (size_t)N * F_H1;
  float* cnts   = pooled + (size_t)G * F_H2;

  hipMemsetAsync(dis, 0, (size_t)N * sizeof(float), stream);
  hipMemsetAsync(B, 0, (size_t)N * F_H1 * sizeof(float), stream);
  hipMemsetAsync(pooled, 0, ((size_t)G * F_H2 + G) * sizeof(float), stream);

  k_deg<<<(E + BLK - 1) / BLK, BLK, 0, stream>>>(dstp, dis, E);
  k_dis<<<(N + BLK - 1) / BLK, BLK, 0, stream>>>(dis, N);
  k_mm1<<<(N + BLK - 1) / BLK, BLK, 0, stream>>>(x, W1, A, N);
  k_edge<F_H1><<<(E * F_H1 + BLK - 1) / BLK, BLK, 0, stream>>>(src, dstp, dis, A, B, E * F_H1);
  k_combine<F_H1><<<(N * F_H1 + BLK - 1) / BLK, BLK, 0, stream>>>(A, dis, b1, B, N * F_H1);
  hipMemsetAsync(agg2, 0, (size_t)N * F_H2 * sizeof(float), stream);
  k_mm2<<<(N + BLK - 1) / BLK, BLK, 0, stream>>>(B, W2, h2, N);
  k_edge<F_H2><<<(E * F_H2 + BLK - 1) / BLK, BLK, 0, stream>>>(src, dstp, dis, h2, agg2, E * F_H2);
  k_combine_pool_fb<<<(N * F_H2 + BLK - 1) / BLK, BLK, 0, stream>>>(
      h2, agg2, dis, b2, batch, pooled, cnts, N * F_H2);
  k_final<<<(G * N_CLS + BLK - 1) / BLK, BLK, 0, stream>>>(
      pooled, cnts, Wl, bl, (float*)d_out, G * N_CLS);
}